// Round 14
// baseline (274.294 us; speedup 1.0000x reference)
//
#include <hip/hip_runtime.h>
#include <stdint.h>

typedef unsigned short u16;

#define BB 2
#define NN 2048
#define MM 2048
#define CC 512
#define KK 16
#define KK1 8
#define KEY 1024

typedef __attribute__((ext_vector_type(8))) short bf16x8;
typedef __attribute__((ext_vector_type(4))) float f32x4;

__device__ __forceinline__ float b2f(u16 u){ return __uint_as_float(((uint32_t)u) << 16); }
__device__ __forceinline__ u16 f2b(float f){
  uint32_t x = __float_as_uint(f);
  uint32_t r = x + 0x7FFFu + ((x >> 16) & 1u);
  return (u16)(r >> 16);
}
__device__ __forceinline__ float sane(float v){ return (fabsf(v) < 1e30f) ? v : 1e30f; }

// async global->LDS 16B per lane: LDS dest = wave-uniform base + lane*16 (HW rule)
__device__ __forceinline__ void gload_lds16(const u16* g, u16* l){
  __builtin_amdgcn_global_load_lds((const __attribute__((address_space(1))) uint32_t*)g,
                                   (__attribute__((address_space(3))) uint32_t*)l, 16, 0, 0);
}
__device__ __forceinline__ void gload_lds16f(const float* g, float* l){
  __builtin_amdgcn_global_load_lds((const __attribute__((address_space(1))) uint32_t*)g,
                                   (__attribute__((address_space(3))) uint32_t*)l, 16, 0, 0);
}

// all-thread block reduction, 256 threads. op: 0=sum 1=min 2=max
__device__ __forceinline__ float blockRed(float v, float* red, int t, int op){
  red[t] = v; __syncthreads();
  #pragma unroll
  for (int s = 128; s > 0; s >>= 1){
    if (t < s){
      float a = red[t], b = red[t + s];
      red[t] = (op == 0) ? (a + b) : ((op == 1) ? fminf(a, b) : fmaxf(a, b));
    }
    __syncthreads();
  }
  float r = red[0]; __syncthreads();
  return r;
}

// 4-wide sum tree; per-component order identical to 4 separate blockReds -> each
// component's result is bit-identical to blockRed(v, red, t, 0).
__device__ __forceinline__ f32x4 blockRed4(f32x4 v, f32x4* red4, int t){
  red4[t] = v; __syncthreads();
  #pragma unroll
  for (int s = 128; s > 0; s >>= 1){
    if (t < s){
      f32x4 a = red4[t], c = red4[t + s];
      a.x += c.x; a.y += c.y; a.z += c.z; a.w += c.w;
      red4[t] = a;
    }
    __syncthreads();
  }
  f32x4 r = red4[0]; __syncthreads();
  return r;
}

// exact block min (min is associative+commutative; inputs sane()-filtered so no NaN;
// ±0 ties only feed expf(x-y) where both zero signs give identical bits). 1 barrier.
__device__ __forceinline__ float blockMinExact(float v, float* wmin, int t){
  #pragma unroll
  for (int off = 1; off < 64; off <<= 1) v = fminf(v, __shfl_xor(v, off));
  if ((t & 63) == 0) wmin[t >> 6] = v;
  __syncthreads();
  return fminf(fminf(wmin[0], wmin[1]), fminf(wmin[2], wmin[3]));
}

// ---- K0: transpose f32 (B,C,N) -> split-bf16 (B,N,C) hi/lo pairs -------------------
__global__ __launch_bounds__(256) void k_trans(const float* __restrict__ semb, const float* __restrict__ temb,
                                               u16* __restrict__ Ah, u16* __restrict__ Al,
                                               u16* __restrict__ Bh, u16* __restrict__ Bl){
  __shared__ float tile[32][33];
  int b = blockIdx.z & 1, which = blockIdx.z >> 1;
  const float* in = which ? temb : semb;
  u16* oh = which ? Bh : Ah;
  u16* ol = which ? Bl : Al;
  int c0 = blockIdx.x * 32, n0 = blockIdx.y * 32;
  int tx = threadIdx.x, ty = threadIdx.y;
  #pragma unroll
  for (int i = 0; i < 4; i++){
    int r = ty + 8 * i;
    tile[r][tx] = in[((b * CC + c0 + r) * NN) + n0 + tx];
  }
  __syncthreads();
  #pragma unroll
  for (int i = 0; i < 4; i++){
    int r = ty + 8 * i;
    float v = tile[tx][r];
    u16 hi = f2b(v);
    float lo = v - b2f(hi);
    size_t o = ((size_t)(b * NN + n0 + r) * CC) + c0 + tx;
    oh[o] = hi;
    ol[o] = f2b(lo);
  }
}

// ---- K1: exact f32 row squared norms (R18 lesson: no FP change ahead of a discrete
// selection; only bit-identical transforms admissible) -------------------------------
__global__ __launch_bounds__(256) void k_sq(const float* __restrict__ semb, const float* __restrict__ temb,
                                            float* __restrict__ xx, float* __restrict__ yy){
  int which = blockIdx.y;
  const float* in = which ? temb : semb;
  float* out = which ? yy : xx;
  int gid = blockIdx.x * 256 + threadIdx.x;   // 0..4095
  int b = gid >> 11, n = gid & 2047;
  float acc = 0.f;
  for (int c = 0; c < CC; c++){
    float v = in[((size_t)(b * CC + c)) * NN + n];
    acc += v * v;
  }
  out[gid] = acc;
}

// ---- K2: dist = xx - 2*A.B^T + yy, split-bf16 MFMA; gload_lds staging (R20) --------
__global__ __launch_bounds__(256) void k_gemm(const u16* __restrict__ Ah, const u16* __restrict__ Al,
                                              const u16* __restrict__ Bh, const u16* __restrict__ Bl,
                                              const float* __restrict__ xx, const float* __restrict__ yy,
                                              float* __restrict__ dist){
  __shared__ __align__(16) u16 lAh[128 * 64];
  __shared__ __align__(16) u16 lAl[128 * 64];
  __shared__ __align__(16) u16 lBh[128 * 64];
  __shared__ __align__(16) u16 lBl[128 * 64];
  int bz = blockIdx.z;
  const u16* Ahb = Ah + (size_t)bz * NN * CC;
  const u16* Alb = Al + (size_t)bz * NN * CC;
  const u16* Bhb = Bh + (size_t)bz * MM * CC;
  const u16* Blb = Bl + (size_t)bz * MM * CC;
  const float* xxb = xx + bz * NN;
  const float* yyb = yy + bz * MM;
  float* distb = dist + (size_t)bz * NN * MM;
  int n0 = blockIdx.y * 128, m0 = blockIdx.x * 128;
  int t = threadIdx.x;
  f32x4 acc[4][4];
  #pragma unroll
  for (int i = 0; i < 4; i++)
    #pragma unroll
    for (int j = 0; j < 4; j++){ f32x4 z = {0.f, 0.f, 0.f, 0.f}; acc[i][j] = z; }
  int w = t >> 6, lane = t & 63, lr = lane & 15, quad = lane >> 4;
  int wn = (w >> 1) * 64, wm = (w & 1) * 64;
  for (int kt = 0; kt < 8; kt++){
    int k0 = kt * 64;
    __syncthreads();
    #pragma unroll
    for (int s = 0; s < 4; s++){
      int ch = t + 256 * s;
      int rn = ch >> 3, k8 = (ch & 7) * 8;
      size_t oa = (size_t)(n0 + rn) * CC + k0 + k8;
      size_t ob = (size_t)(m0 + rn) * CC + k0 + k8;
      int ldsoff = ((t >> 6) * 64 + 256 * s) * 8;   // wave-uniform (u16 elems)
      gload_lds16(Ahb + oa, &lAh[ldsoff]);
      gload_lds16(Alb + oa, &lAl[ldsoff]);
      gload_lds16(Bhb + ob, &lBh[ldsoff]);
      gload_lds16(Blb + ob, &lBl[ldsoff]);
    }
    __syncthreads();
    #pragma unroll
    for (int kk = 0; kk < 2; kk++){
      int off = kk * 32 + quad * 8;
      bf16x8 afh[4], afl[4], bfh[4], bfl[4];
      #pragma unroll
      for (int i = 0; i < 4; i++){
        int ra = (wn + i * 16 + lr) * 64 + off;
        afh[i] = *(const bf16x8*)&lAh[ra];
        afl[i] = *(const bf16x8*)&lAl[ra];
      }
      #pragma unroll
      for (int j = 0; j < 4; j++){
        int rb = (wm + j * 16 + lr) * 64 + off;
        bfh[j] = *(const bf16x8*)&lBh[rb];
        bfl[j] = *(const bf16x8*)&lBl[rb];
      }
      #pragma unroll
      for (int i = 0; i < 4; i++)
        #pragma unroll
        for (int j = 0; j < 4; j++){
          acc[i][j] = __builtin_amdgcn_mfma_f32_16x16x32_bf16(afh[i], bfh[j], acc[i][j], 0, 0, 0);
          acc[i][j] = __builtin_amdgcn_mfma_f32_16x16x32_bf16(afh[i], bfl[j], acc[i][j], 0, 0, 0);
          acc[i][j] = __builtin_amdgcn_mfma_f32_16x16x32_bf16(afl[i], bfh[j], acc[i][j], 0, 0, 0);
        }
    }
  }
  #pragma unroll
  for (int i = 0; i < 4; i++){
    int nbase = n0 + wn + i * 16 + quad * 4;
    #pragma unroll
    for (int j = 0; j < 4; j++){
      int m = m0 + wm + j * 16 + lr;
      float yv = yyb[m];
      #pragma unroll
      for (int r = 0; r < 4; r++){
        distb[((size_t)(nbase + r)) * MM + m] = xxb[nbase + r] + yv - 2.0f * acc[i][j][r];
      }
    }
  }
}

// ---- K3: per-row min, softmax denom, scores row (R17/R21/R24) ----------------------
__global__ __launch_bounds__(256, 4) void k_rowstats(const float* __restrict__ dist,
                                                     float* __restrict__ mnA, float* __restrict__ Zr,
                                                     float* __restrict__ scores){
  __shared__ float red[256];
  __shared__ float wmin[4];
  int row = blockIdx.x, b = blockIdx.y, t = threadIdx.x;
  const float* dr = dist + ((size_t)b * NN + row) * MM;
  float* sr = scores + ((size_t)b * NN + row) * MM;
  float d[8];
  float mn = 3.4e38f;
  #pragma unroll
  for (int i = 0; i < 8; i++){ d[i] = sane(dr[t + 256 * i]); mn = fminf(mn, d[i]); }
  mn = blockMinExact(mn, wmin, t);
  float p[8];
  float z = 0.f;
  #pragma unroll
  for (int i = 0; i < 8; i++){ p[i] = expf(mn - d[i]); z += p[i]; }
  z = blockRed(z, red, t, 0);
  float zc = fmaxf(z, 1e-30f);
  if (t == 0){ mnA[b * NN + row] = mn; Zr[b * NN + row] = zc; }
  float iz = 1.0f / zc;
  #pragma unroll
  for (int i = 0; i < 8; i++) sr[t + 256 * i] = p[i] * iz;
}

// ---- K4: fused T/S/refined/rmm/src_corr/loss. R26: R24 (launch_bounds) and R25
// (register staging) both NULLED — VGPR pinned at 32, compiler folds staging into a
// shallow rolling window -> ~2 loads in flight -> latency-bound at 33% HBM.
// New mechanism: ASYNC DMA staging. global_load_lds issues consume no VGPRs and
// queue deeply: stage all 7 score rows (56KB) into LDS (14 issues/thread, linear
// dest = wave-uniform base + lane*16B, the R20-verified pattern), drain once, then
// accumulate from LDS in the ORIGINAL ascending j-order -> bit-identical tacc.
// Tradeoff: LDS 8.7 -> 65.5KB (2 blocks/CU, occupancy ~25%) vs 56KB in flight/block.
__global__ __launch_bounds__(256, 2) void k_fused(const float* __restrict__ dist, const float* __restrict__ scores,
                                                  const int* __restrict__ sidx1,
                                                  const int* __restrict__ idx2, const float* __restrict__ tgt,
                                                  float* __restrict__ s_corr, float* __restrict__ lossr){
  __shared__ __align__(16) float lrow[7][MM];   // 57344 B staged score rows
  __shared__ float Trow[MM];
  __shared__ float wmin[4];
  int n = blockIdx.x, b = blockIdx.y, t = threadIdx.x;
  const float* distb = dist + (size_t)b * NN * MM;
  const float* scoresb = scores + (size_t)b * NN * MM;
  const int* sidx1b = sidx1 + (size_t)b * NN * KK1;
  const int* idx2b = idx2 + (size_t)b * MM * KK1;
  const float* tgtb = tgt + (size_t)b * 3 * MM;
  float* s_corrb = s_corr + (size_t)b * 3 * NN;
  float* lossb = lossr + b * NN;
  const int4* i1v = (const int4*)(sidx1b + n * KK1);
  int4 i1a = i1v[0], i1b = i1v[1];
  int rj[7] = {i1a.y & 2047, i1a.z & 2047, i1a.w & 2047,
               i1b.x & 2047, i1b.y & 2047, i1b.z & 2047, i1b.w & 2047};
  // issue all async row stages first (56KB in flight, no VGPR cost)
  #pragma unroll
  for (int j = 0; j < 7; j++){
    const float* srp = scoresb + (size_t)rj[j] * MM;
    #pragma unroll
    for (int s = 0; s < 2; s++){
      int ch = t + 256 * s;                       // 512 chunks x 16B = 8192B
      int ldsoff = ((t >> 6) * 64 + 256 * s) * 4; // wave-uniform base (floats)
      gload_lds16f(srp + ch * 4, &lrow[j][ldsoff]);
    }
  }
  // dist row loads overlap the DMA
  const float* dn_p = distb + (size_t)n * MM;
  float dn[8];
  #pragma unroll
  for (int i = 0; i < 8; i++) dn[i] = sane(dn_p[t + 256 * i]);
  __syncthreads();   // drains vmcnt -> staged rows ready
  // accumulate in the ORIGINAL j-order (left fold from 0) -> bit-identical tacc
  float tacc[8];
  #pragma unroll
  for (int i = 0; i < 8; i++){
    float s = 0.f;
    #pragma unroll
    for (int j = 0; j < 7; j++) s += lrow[j][t + 256 * i];
    tacc[i] = s;
  }
  #pragma unroll
  for (int i = 0; i < 8; i++) Trow[t + 256 * i] = tacc[i];
  __syncthreads();
  float rloc[8];
  float lmin = 3.4e38f;
  #pragma unroll
  for (int i = 0; i < 8; i++){
    int m = t + 256 * i;
    const int4* ipv = (const int4*)(idx2b + m * KK1);
    int4 ipa = ipv[0], ipb = ipv[1];
    float S = 0.f;
    S += Trow[ipa.y & 2047];
    S += Trow[ipa.z & 2047];
    S += Trow[ipa.w & 2047];
    S += Trow[ipb.x & 2047];
    S += Trow[ipb.y & 2047];
    S += Trow[ipb.z & 2047];
    S += Trow[ipb.w & 2047];
    float rv = sane(expf(1.0f - S / 7.0f) * dn[i]);
    rloc[i] = rv;
    lmin = fminf(lmin, rv);
  }
  // exact min; its barrier also guarantees all Trow reads finished before reuse
  float rmin = blockMinExact(lmin, wmin, t);
  float z = 0.f, s0 = 0.f, s1 = 0.f, s2 = 0.f;
  #pragma unroll
  for (int i = 0; i < 8; i++){
    int m = t + 256 * i;
    float p = expf(rmin - rloc[i]);
    z  += p;
    s0 += tgtb[0 * MM + m] * p;
    s1 += tgtb[1 * MM + m] * p;
    s2 += tgtb[2 * MM + m] * p;
  }
  f32x4 v4; v4.x = z; v4.y = s0; v4.z = s1; v4.w = s2;
  f32x4 r = blockRed4(v4, (f32x4*)Trow, t);   // Trow dead; identical tree order
  if (t == 0){
    float iZ = 1.0f / fmaxf(r.x, 1e-30f);
    s_corrb[0 * NN + n] = r.y * iZ;
    s_corrb[1 * NN + n] = r.z * iZ;
    s_corrb[2 * NN + n] = r.w * iZ;
    lossb[n] = -logf(fminf(iZ, 1.0f) + 1e-15f);  // pred at onehot == rowmax(rmm) == 1/Z
  }
}

// ---- K5: discriminator MLP — R14: scalar-W2 + e-range wave split -------------------
__global__ __launch_bounds__(256, 4) void k_disc(const float* __restrict__ s_corr, const float* __restrict__ src,
                                                 const float* __restrict__ sknn, const int* __restrict__ sidx,
                                                 const float* __restrict__ W1, const float* __restrict__ b1,
                                                 const float* __restrict__ W2, const float* __restrict__ b2,
                                                 const float* __restrict__ W3, const float* __restrict__ b3,
                                                 float* __restrict__ sArr){
  __shared__ float term[64][129];
  int t = threadIdx.x;
  int b = blockIdx.y;
  int p = t & 63;
  int n = blockIdx.x * 4 + (p >> 4);
  int kk = p & 15;
  int eh = t >> 6;
  int nk = sidx[((b * NN + n) * KK) + kk] & 2047;
  float f[6];
  #pragma unroll
  for (int c = 0; c < 3; c++){
    f[c]     = s_corr[(b * 3 + c) * NN + n] - s_corr[(b * 3 + c) * NN + nk];
    f[3 + c] = src[(b * 3 + c) * NN + n] - sknn[((size_t)(b * NN + n) * KK + kk) * 3 + c];
  }
  #define L1D(d) ({ float a_ = b1[(d)];              \
                    a_ += f[0] * W1[(d) * 6 + 0];    \
                    a_ += f[1] * W1[(d) * 6 + 1];    \
                    a_ += f[2] * W1[(d) * 6 + 2];    \
                    a_ += f[3] * W1[(d) * 6 + 3];    \
                    a_ += f[4] * W1[(d) * 6 + 4];    \
                    a_ += f[5] * W1[(d) * 6 + 5];    \
                    fmaxf(a_, 0.f); })
  #define HSET(i) f32x4 h##i;                  \
                  h##i.x = L1D(4 * (i) + 0);   \
                  h##i.y = L1D(4 * (i) + 1);   \
                  h##i.z = L1D(4 * (i) + 2);   \
                  h##i.w = L1D(4 * (i) + 3);
  HSET(0) HSET(1) HSET(2) HSET(3) HSET(4) HSET(5) HSET(6) HSET(7)
  HSET(8) HSET(9) HSET(10) HSET(11) HSET(12) HSET(13) HSET(14) HSET(15)
  #undef HSET
  #undef L1D
  int e0 = __builtin_amdgcn_readfirstlane(eh * 32);
  for (int j = 0; j < 32; j++){
    int e = e0 + j;
    float a = b2[e];
    const f32x4* w4 = (const f32x4*)&W2[e * 64];
    #define QSTEP(i) { f32x4 wv = w4[i]; a += wv.x * h##i.x + wv.y * h##i.y + wv.z * h##i.z + wv.w * h##i.w; }
    QSTEP(0) QSTEP(1) QSTEP(2) QSTEP(3) QSTEP(4) QSTEP(5) QSTEP(6) QSTEP(7)
    QSTEP(8) QSTEP(9) QSTEP(10) QSTEP(11) QSTEP(12) QSTEP(13) QSTEP(14) QSTEP(15)
    #undef QSTEP
    term[p][e] = fmaxf(a, 0.f);
  }
  __syncthreads();
  if (t < 64){
    float sacc = b3[0];
    #pragma unroll 4
    for (int e = 0; e < 128; e++) sacc += W3[e] * term[t][e];
    if (!(fabsf(sacc) < 1e30f)) sacc = -1e30f;
    #pragma unroll
    for (int off = 1; off < 16; off <<= 1) sacc = fmaxf(sacc, __shfl_xor(sacc, off, 16));
    if (kk == 0) sArr[b * NN + n] = sacc;
  }
}

// ---- K6+K7+K8 merged (R21/R22/R23 structure; f32 SVD, named scalars) ---------------
__global__ __launch_bounds__(256) void k_rankrig(const float* __restrict__ sArr, const float* __restrict__ src,
                                                 const float* __restrict__ s_corr, int* __restrict__ topi,
                                                 float* __restrict__ Rt, float* __restrict__ out){
  __shared__ float wrow[NN];
  __shared__ float red[256];
  __shared__ f32x4 red4[256];
  __shared__ int pc[4][64];
  int b = blockIdx.y, t = threadIdx.x;
  // ---- softmax (verbatim k_softw) -> wrow (feeds rank -> topi: DISCRETE, verbatim) --
  const float* sp = sArr + b * NN;
  float sv[8];
  float mx = -3.4e38f;
  #pragma unroll
  for (int i = 0; i < 8; i++){
    float v = sp[t + 256 * i];
    if (!(fabsf(v) < 1e30f)) v = -1e30f;
    sv[i] = v; mx = fmaxf(mx, v);
  }
  mx = blockRed(mx, red, t, 2);
  float z = 0.f;
  #pragma unroll
  for (int i = 0; i < 8; i++) z += expf(sv[i] - mx);
  z = blockRed(z, red, t, 0);
  float iz = 1.0f / fmaxf(z, 1e-30f);
  #pragma unroll
  for (int i = 0; i < 8; i++) wrow[t + 256 * i] = expf(sv[i] - mx) * iz;
  __syncthreads();
  // ---- rank (verbatim R15 body) ----
  int tn = t & 63, tj = t >> 6;
  int n = blockIdx.x * 64 + tn;
  float wn = wrow[n];
  int j0 = tj * 512;
  const f32x4* w4 = (const f32x4*)&wrow[j0];
  int cnt = 0;
  #pragma unroll 4
  for (int q = 0; q < 128; q++){
    f32x4 wv = w4[q];
    int j = j0 + q * 4;
    cnt += (wv.x > wn) || ((wv.x == wn) && (j + 0 < n));
    cnt += (wv.y > wn) || ((wv.y == wn) && (j + 1 < n));
    cnt += (wv.z > wn) || ((wv.z == wn) && (j + 2 < n));
    cnt += (wv.w > wn) || ((wv.w == wn) && (j + 3 < n));
  }
  pc[tj][tn] = cnt;
  __syncthreads();
  if (t < 64){
    int c = pc[0][t] + pc[1][t] + pc[2][t] + pc[3][t];
    if (c < KEY) topi[b * KEY + c] = blockIdx.x * 64 + t;
  }
  if (blockIdx.x != 0) return;
  // ---- rigid: centroids + H via blockRed4 (bit-identical sums) ----
  float wsum = 0, a0 = 0, a1 = 0, a2 = 0, c0 = 0, c1 = 0, c2 = 0;
  for (int n2 = t; n2 < NN; n2 += 256){
    float wv = wrow[n2];
    float s0 = src[(b * 3 + 0) * NN + n2];
    float s1 = src[(b * 3 + 1) * NN + n2];
    float s2 = src[(b * 3 + 2) * NN + n2];
    float q0 = s_corr[(b * 3 + 0) * NN + n2];
    float q1 = s_corr[(b * 3 + 1) * NN + n2];
    float q2 = s_corr[(b * 3 + 2) * NN + n2];
    wsum += wv; a0 += wv * s0; a1 += wv * s1; a2 += wv * s2;
    c0 += wv * q0; c1 += wv * q1; c2 += wv * q2;
  }
  f32x4 pk1; pk1.x = wsum; pk1.y = a0; pk1.z = a1; pk1.w = a2;
  pk1 = blockRed4(pk1, red4, t);
  f32x4 pk2; pk2.x = c0; pk2.y = c1; pk2.z = c2; pk2.w = 0.f;
  pk2 = blockRed4(pk2, red4, t);
  wsum = pk1.x; a0 = pk1.y; a1 = pk1.z; a2 = pk1.w;
  c0 = pk2.x; c1 = pk2.y; c2 = pk2.z;
  float inv = 1.0f / fmaxf(wsum, 1e-30f);
  float cs0 = a0 * inv, cs1 = a1 * inv, cs2 = a2 * inv;
  float ct0 = c0 * inv, ct1 = c1 * inv, ct2 = c2 * inv;
  float h[9] = {0, 0, 0, 0, 0, 0, 0, 0, 0};
  for (int n2 = t; n2 < NN; n2 += 256){
    float wv = wrow[n2];
    float ds0 = src[(b * 3 + 0) * NN + n2] - cs0;
    float ds1 = src[(b * 3 + 1) * NN + n2] - cs1;
    float ds2 = src[(b * 3 + 2) * NN + n2] - cs2;
    float dc0 = s_corr[(b * 3 + 0) * NN + n2] - ct0;
    float dc1 = s_corr[(b * 3 + 1) * NN + n2] - ct1;
    float dc2 = s_corr[(b * 3 + 2) * NN + n2] - ct2;
    h[0] += wv * ds0 * dc0; h[1] += wv * ds0 * dc1; h[2] += wv * ds0 * dc2;
    h[3] += wv * ds1 * dc0; h[4] += wv * ds1 * dc1; h[5] += wv * ds1 * dc2;
    h[6] += wv * ds2 * dc0; h[7] += wv * ds2 * dc1; h[8] += wv * ds2 * dc2;
  }
  f32x4 ph1; ph1.x = h[0]; ph1.y = h[1]; ph1.z = h[2]; ph1.w = h[3];
  ph1 = blockRed4(ph1, red4, t);
  f32x4 ph2; ph2.x = h[4]; ph2.y = h[5]; ph2.z = h[6]; ph2.w = h[7];
  ph2 = blockRed4(ph2, red4, t);
  float h8 = blockRed(h[8], red, t, 0);
  if (t == 0){
    // ---- all-register 3x3 SVD, f32 (static pivot enumeration) ----
    float Hm00 = ph1.x, Hm01 = ph1.y, Hm02 = ph1.z;
    float Hm10 = ph1.w, Hm11 = ph2.x, Hm12 = ph2.y;
    float Hm20 = ph2.z, Hm21 = ph2.w, Hm22 = h8;
    float k00 = Hm00 * Hm00 + Hm10 * Hm10 + Hm20 * Hm20;
    float k01 = Hm00 * Hm01 + Hm10 * Hm11 + Hm20 * Hm21;
    float k02 = Hm00 * Hm02 + Hm10 * Hm12 + Hm20 * Hm22;
    float k10 = k01, k11 = Hm01 * Hm01 + Hm11 * Hm11 + Hm21 * Hm21;
    float k12 = Hm01 * Hm02 + Hm11 * Hm12 + Hm21 * Hm22;
    float k20 = k02, k21 = k12;
    float k22 = Hm02 * Hm02 + Hm12 * Hm12 + Hm22 * Hm22;
    float v00 = 1, v01 = 0, v02 = 0, v10 = 0, v11 = 1, v12 = 0, v20 = 0, v21 = 0, v22 = 1;
    float ksc = fabsf(k00) + fabsf(k11) + fabsf(k22) + 1e-30f;
    #define ROT2(A, B) { float ra = A, rb = B; A = cc2 * ra - sn * rb; B = sn * ra + cc2 * rb; }
    for (int sweep = 0; sweep < 30; sweep++){
      float m01 = fabsf(k01), m02 = fabsf(k02), m12 = fabsf(k12);
      int cse = 0; float mx2 = m01;
      if (m02 > mx2){ mx2 = m02; cse = 1; }
      if (m12 > mx2){ mx2 = m12; cse = 2; }
      if (mx2 <= 1e-6f * ksc) break;
      float app, aqq, apq;
      if (cse == 0){ app = k00; aqq = k11; apq = k01; }
      else if (cse == 1){ app = k00; aqq = k22; apq = k02; }
      else { app = k11; aqq = k22; apq = k12; }
      float tau = (aqq - app) / (2.0f * apq);
      float tt = ((tau >= 0) ? 1.0f : -1.0f) / (fabsf(tau) + sqrtf(1.0f + tau * tau));
      float cc2 = 1.0f / sqrtf(1.0f + tt * tt), sn = tt * cc2;
      if (cse == 0){        // (p,q)=(0,1)
        ROT2(k00, k01) ROT2(k10, k11) ROT2(k20, k21)
        ROT2(k00, k10) ROT2(k01, k11) ROT2(k02, k12)
        ROT2(v00, v01) ROT2(v10, v11) ROT2(v20, v21)
      } else if (cse == 1){ // (p,q)=(0,2)
        ROT2(k00, k02) ROT2(k10, k12) ROT2(k20, k22)
        ROT2(k00, k20) ROT2(k01, k21) ROT2(k02, k22)
        ROT2(v00, v02) ROT2(v10, v12) ROT2(v20, v22)
      } else {              // (p,q)=(1,2)
        ROT2(k01, k02) ROT2(k11, k12) ROT2(k21, k22)
        ROT2(k10, k20) ROT2(k11, k21) ROT2(k12, k22)
        ROT2(v01, v02) ROT2(v11, v12) ROT2(v21, v22)
      }
    }
    #undef ROT2
    float l0 = k00, l1 = k11, l2 = k22; int id0 = 0, id1 = 1, id2 = 2;
    float lt; int it;
    if (l0 < l1){ lt = l0; l0 = l1; l1 = lt; it = id0; id0 = id1; id1 = it; }
    if (l0 < l2){ lt = l0; l0 = l2; l2 = lt; it = id0; id0 = id2; id2 = it; }
    if (l1 < l2){ lt = l1; l1 = l2; l2 = lt; it = id1; id1 = id2; id2 = it; }
    float Vs00, Vs10, Vs20, Vs01, Vs11, Vs21, Vs02, Vs12, Vs22;
    float u00 = 0, u10 = 0, u20 = 0, u01 = 0, u11 = 0, u21 = 0, u02 = 0, u12 = 0, u22 = 0;
    #define GETCOL(j, cA, cB, cC) { if ((j) == 0){ cA = v00; cB = v10; cC = v20; } \
                                    else if ((j) == 1){ cA = v01; cB = v11; cC = v21; } \
                                    else { cA = v02; cB = v12; cC = v22; } }
    {
      float cA, cB, cC; GETCOL(id0, cA, cB, cC);
      Vs00 = cA; Vs10 = cB; Vs20 = cC;
      float uu0 = Hm00 * cA + Hm01 * cB + Hm02 * cC;
      float uu1 = Hm10 * cA + Hm11 * cB + Hm12 * cC;
      float uu2 = Hm20 * cA + Hm21 * cB + Hm22 * cC;
      float nrm = sqrtf(uu0 * uu0 + uu1 * uu1 + uu2 * uu2);
      if (nrm > 1e-20f){ u00 = uu0 / nrm; u10 = uu1 / nrm; u20 = uu2 / nrm; }
      else { u00 = 1; u10 = 0; u20 = 0; }
    }
    {
      float cA, cB, cC; GETCOL(id1, cA, cB, cC);
      Vs01 = cA; Vs11 = cB; Vs21 = cC;
      float uu0 = Hm00 * cA + Hm01 * cB + Hm02 * cC;
      float uu1 = Hm10 * cA + Hm11 * cB + Hm12 * cC;
      float uu2 = Hm20 * cA + Hm21 * cB + Hm22 * cC;
      float nrm = sqrtf(uu0 * uu0 + uu1 * uu1 + uu2 * uu2);
      if (nrm > 1e-20f){ u01 = uu0 / nrm; u11 = uu1 / nrm; u21 = uu2 / nrm; }
      else {
        float x0 = u10 * u21 - u20 * u11;
        float x1 = u20 * u01 - u00 * u21;
        float x2 = u00 * u11 - u10 * u01;
        float nn2 = sqrtf(x0 * x0 + x1 * x1 + x2 * x2);
        if (nn2 < 1e-20f){ x0 = 1; x1 = 0; x2 = 0; nn2 = 1; }
        u01 = x0 / nn2; u11 = x1 / nn2; u21 = x2 / nn2;
      }
    }
    {
      float cA, cB, cC; GETCOL(id2, cA, cB, cC);
      Vs02 = cA; Vs12 = cB; Vs22 = cC;
      float uu0 = Hm00 * cA + Hm01 * cB + Hm02 * cC;
      float uu1 = Hm10 * cA + Hm11 * cB + Hm12 * cC;
      float uu2 = Hm20 * cA + Hm21 * cB + Hm22 * cC;
      float nrm = sqrtf(uu0 * uu0 + uu1 * uu1 + uu2 * uu2);
      if (nrm > 1e-20f){ u02 = uu0 / nrm; u12 = uu1 / nrm; u22 = uu2 / nrm; }
      else {
        float x0 = u10 * u21 - u20 * u11;
        float x1 = u20 * u01 - u00 * u21;
        float x2 = u00 * u11 - u10 * u01;
        float nn2 = sqrtf(x0 * x0 + x1 * x1 + x2 * x2);
        if (nn2 < 1e-20f){ x0 = 1; x1 = 0; x2 = 0; nn2 = 1; }
        u02 = x0 / nn2; u12 = x1 / nn2; u22 = x2 / nn2;
      }
    }
    #undef GETCOL
    float ddU = u00 * (u11 * u22 - u12 * u21) - u01 * (u10 * u22 - u12 * u20) + u02 * (u10 * u21 - u11 * u20);
    float ddV = Vs00 * (Vs11 * Vs22 - Vs12 * Vs21) - Vs01 * (Vs10 * Vs22 - Vs12 * Vs20) + Vs02 * (Vs10 * Vs21 - Vs11 * Vs20);
    float dd = ddU * ddV;
    float Rm00 = Vs00 * u00 + Vs01 * u01 + dd * Vs02 * u02;
    float Rm01 = Vs00 * u10 + Vs01 * u11 + dd * Vs02 * u12;
    float Rm02 = Vs00 * u20 + Vs01 * u21 + dd * Vs02 * u22;
    float Rm10 = Vs10 * u00 + Vs11 * u01 + dd * Vs12 * u02;
    float Rm11 = Vs10 * u10 + Vs11 * u11 + dd * Vs12 * u12;
    float Rm12 = Vs10 * u20 + Vs11 * u21 + dd * Vs12 * u22;
    float Rm20 = Vs20 * u00 + Vs21 * u01 + dd * Vs22 * u02;
    float Rm21 = Vs20 * u10 + Vs21 * u11 + dd * Vs22 * u12;
    float Rm22 = Vs20 * u20 + Vs21 * u21 + dd * Vs22 * u22;
    float tv0 = ct0 - (Rm00 * cs0 + Rm01 * cs1 + Rm02 * cs2);
    float tv1 = ct1 - (Rm10 * cs0 + Rm11 * cs1 + Rm12 * cs2);
    float tv2 = ct2 - (Rm20 * cs0 + Rm21 * cs1 + Rm22 * cs2);
    Rt[b * 12 + 0] = Rm00; out[b * 9 + 0] = Rm00;
    Rt[b * 12 + 1] = Rm01; out[b * 9 + 1] = Rm01;
    Rt[b * 12 + 2] = Rm02; out[b * 9 + 2] = Rm02;
    Rt[b * 12 + 3] = Rm10; out[b * 9 + 3] = Rm10;
    Rt[b * 12 + 4] = Rm11; out[b * 9 + 4] = Rm11;
    Rt[b * 12 + 5] = Rm12; out[b * 9 + 5] = Rm12;
    Rt[b * 12 + 6] = Rm20; out[b * 9 + 6] = Rm20;
    Rt[b * 12 + 7] = Rm21; out[b * 9 + 7] = Rm21;
    Rt[b * 12 + 8] = Rm22; out[b * 9 + 8] = Rm22;
    Rt[b * 12 + 9]  = tv0; out[18 + b * 3 + 0] = tv0;
    Rt[b * 12 + 10] = tv1; out[18 + b * 3 + 1] = tv1;
    Rt[b * 12 + 11] = tv2; out[18 + b * 3 + 2] = tv2;
  }
}

// ---- K10 (+K11 merged): keypoint gathers; block x==64,b==0 computes loss_scl -------
__global__ __launch_bounds__(256) void k_out(const int* __restrict__ topi, const int* __restrict__ sidx,
                                             const float* __restrict__ src, const float* __restrict__ s_corr,
                                             const float* __restrict__ Rt, const float* __restrict__ loss_row,
                                             float* __restrict__ out){
  __shared__ float red[256];
  int b = blockIdx.y, t = threadIdx.x;
  if (blockIdx.x == 64){
    if (b != 0) return;
    float acc = 0.f;
    for (int i = t; i < BB * KEY; i += 256){
      int bb = i >> 10, r = i & 1023;
      int n = topi[bb * KEY + r] & 2047;
      acc += loss_row[bb * NN + n];
    }
    acc = blockRed(acc, red, t, 0);
    if (t == 0) out[208920] = acc / 2048.0f;
    return;
  }
  int rr = t >> 4, kk = t & 15;
  int r = blockIdx.x * 16 + rr;
  int ns = topi[b * KEY + r] & 2047;
  int nk = sidx[(b * NN + ns) * KK + kk] & 2047;
  const float* R = Rt + b * 12;
  float sns0 = src[(b * 3 + 0) * NN + ns];
  float sns1 = src[(b * 3 + 1) * NN + ns];
  float sns2 = src[(b * 3 + 2) * NN + ns];
  float snk0 = src[(b * 3 + 0) * NN + nk];
  float snk1 = src[(b * 3 + 1) * NN + nk];
  float snk2 = src[(b * 3 + 2) * NN + nk];
  float* o_sk  = out + 24;
  float* o_tk  = out + 6168;
  float* o_skk = out + 12312;
  float* o_tkk = out + 110616;
  #pragma unroll
  for (int c = 0; c < 3; c++){
    float cv  = s_corr[(b * 3 + c) * NN + ns];
    float ck  = s_corr[(b * 3 + c) * NN + nk];
    o_tkk[(((b * 3 + c) * KEY + r) * KK) + kk] = cv - ck;
    float sv  = R[c * 3 + 0] * sns0 + R[c * 3 + 1] * sns1 + R[c * 3 + 2] * sns2 + R[9 + c];
    float sk2 = R[c * 3 + 0] * snk0 + R[c * 3 + 1] * snk1 + R[c * 3 + 2] * snk2 + R[9 + c];
    o_skk[(((b * 3 + c) * KEY + r) * KK) + kk] = sv - sk2;
    if (kk == 0){
      o_sk[(b * 3 + c) * KEY + r] = sns0 * (c == 0) + sns1 * (c == 1) + sns2 * (c == 2);
      o_tk[(b * 3 + c) * KEY + r] = cv;
    }
  }
}

extern "C" void kernel_launch(void* const* d_in, const int* in_sizes, int n_in,
                              void* d_out, int out_size, void* d_ws, size_t ws_size,
                              hipStream_t stream){
  const float* src  = (const float*)d_in[0];
  const float* tgt  = (const float*)d_in[1];
  const float* semb = (const float*)d_in[2];
  const float* temb = (const float*)d_in[3];
  const float* sknn = (const float*)d_in[4];
  const float* W1 = (const float*)d_in[6];
  const float* b1 = (const float*)d_in[7];
  const float* W2 = (const float*)d_in[8];
  const float* b2 = (const float*)d_in[9];
  const float* W3 = (const float*)d_in[10];
  const float* b3 = (const float*)d_in[11];
  const int* sidx  = (const int*)d_in[12];
  const int* sidx1 = (const int*)d_in[13];
  const int* idx2  = (const int*)d_in[14];
  float* out = (float*)d_out;

  // workspace layout (peak ~84 MB; harness allocates 256 MiB per fill evidence)
  char* w = (char*)d_ws;
  u16* Ah = (u16*)(w);                               // 4 MB each (B,N,C) bf16 split
  u16* Al = Ah + (size_t)BB * NN * CC;
  u16* Bh = Al + (size_t)BB * NN * CC;
  u16* Bl = Bh + (size_t)BB * MM * CC;
  float* dist = (float*)(Bl + (size_t)BB * MM * CC); // 33.55 MB (B,N,M) f32
  float* scores = dist + (size_t)BB * NN * MM;       // 33.55 MB (B,N,M) f32
  char* tail = (char*)(scores + (size_t)BB * NN * MM);
  float* xx = (float*)tail;                          // B*N
  float* yy = xx + BB * NN;                          // B*M
  float* mnA = yy + BB * MM;                         // B*N
  float* Zr = mnA + BB * NN;                         // B*N
  float* s_corr = Zr + BB * NN;                      // B*3*N
  float* loss_row = s_corr + BB * 3 * NN;            // B*N
  float* sArr = loss_row + BB * NN;                  // B*N
  int* topi = (int*)(sArr + BB * NN);                // B*KEY
  float* Rt = (float*)(topi + BB * KEY);             // B*12

  k_trans<<<dim3(16, 64, 4), dim3(32, 8), 0, stream>>>(semb, temb, Ah, Al, Bh, Bl);
  k_sq<<<dim3(16, 2), 256, 0, stream>>>(semb, temb, xx, yy);
  k_gemm<<<dim3(16, 16, BB), 256, 0, stream>>>(Ah, Al, Bh, Bl, xx, yy, dist);
  k_rowstats<<<dim3(NN, BB), 256, 0, stream>>>(dist, mnA, Zr, scores);
  k_fused<<<dim3(NN, BB), 256, 0, stream>>>(dist, scores, sidx1, idx2, tgt, s_corr, loss_row);
  k_disc<<<dim3(NN / 4, BB), 256, 0, stream>>>(s_corr, src, sknn, sidx, W1, b1, W2, b2, W3, b3, sArr);
  k_rankrig<<<dim3(32, BB), 256, 0, stream>>>(sArr, src, s_corr, topi, Rt, out);
  k_out<<<dim3(65, BB), 256, 0, stream>>>(topi, sidx, src, s_corr, Rt, loss_row, out);
}

// Round 15
// 257.175 us; speedup vs baseline: 1.0666x; 1.0666x over previous
//
#include <hip/hip_runtime.h>
#include <stdint.h>

typedef unsigned short u16;

#define BB 2
#define NN 2048
#define MM 2048
#define CC 512
#define KK 16
#define KK1 8
#define KEY 1024

typedef __attribute__((ext_vector_type(8))) short bf16x8;
typedef __attribute__((ext_vector_type(4))) float f32x4;

__device__ __forceinline__ float b2f(u16 u){ return __uint_as_float(((uint32_t)u) << 16); }
__device__ __forceinline__ u16 f2b(float f){
  uint32_t x = __float_as_uint(f);
  uint32_t r = x + 0x7FFFu + ((x >> 16) & 1u);
  return (u16)(r >> 16);
}
__device__ __forceinline__ float sane(float v){ return (fabsf(v) < 1e30f) ? v : 1e30f; }

// async global->LDS 16B per lane: LDS dest = wave-uniform base + lane*16 (HW rule)
__device__ __forceinline__ void gload_lds16(const u16* g, u16* l){
  __builtin_amdgcn_global_load_lds((const __attribute__((address_space(1))) uint32_t*)g,
                                   (__attribute__((address_space(3))) uint32_t*)l, 16, 0, 0);
}

// all-thread block reduction, 256 threads. op: 0=sum 1=min 2=max
__device__ __forceinline__ float blockRed(float v, float* red, int t, int op){
  red[t] = v; __syncthreads();
  #pragma unroll
  for (int s = 128; s > 0; s >>= 1){
    if (t < s){
      float a = red[t], b = red[t + s];
      red[t] = (op == 0) ? (a + b) : ((op == 1) ? fminf(a, b) : fmaxf(a, b));
    }
    __syncthreads();
  }
  float r = red[0]; __syncthreads();
  return r;
}

// 4-wide sum tree; per-component order identical to 4 separate blockReds -> each
// component's result is bit-identical to blockRed(v, red, t, 0).
__device__ __forceinline__ f32x4 blockRed4(f32x4 v, f32x4* red4, int t){
  red4[t] = v; __syncthreads();
  #pragma unroll
  for (int s = 128; s > 0; s >>= 1){
    if (t < s){
      f32x4 a = red4[t], c = red4[t + s];
      a.x += c.x; a.y += c.y; a.z += c.z; a.w += c.w;
      red4[t] = a;
    }
    __syncthreads();
  }
  f32x4 r = red4[0]; __syncthreads();
  return r;
}

// exact block min (min is associative+commutative; inputs sane()-filtered so no NaN;
// ±0 ties only feed expf(x-y) where both zero signs give identical bits). 1 barrier.
__device__ __forceinline__ float blockMinExact(float v, float* wmin, int t){
  #pragma unroll
  for (int off = 1; off < 64; off <<= 1) v = fminf(v, __shfl_xor(v, off));
  if ((t & 63) == 0) wmin[t >> 6] = v;
  __syncthreads();
  return fminf(fminf(wmin[0], wmin[1]), fminf(wmin[2], wmin[3]));
}

// ---- K0: transpose f32 (B,C,N) -> split-bf16 (B,N,C) hi/lo pairs -------------------
__global__ __launch_bounds__(256) void k_trans(const float* __restrict__ semb, const float* __restrict__ temb,
                                               u16* __restrict__ Ah, u16* __restrict__ Al,
                                               u16* __restrict__ Bh, u16* __restrict__ Bl){
  __shared__ float tile[32][33];
  int b = blockIdx.z & 1, which = blockIdx.z >> 1;
  const float* in = which ? temb : semb;
  u16* oh = which ? Bh : Ah;
  u16* ol = which ? Bl : Al;
  int c0 = blockIdx.x * 32, n0 = blockIdx.y * 32;
  int tx = threadIdx.x, ty = threadIdx.y;
  #pragma unroll
  for (int i = 0; i < 4; i++){
    int r = ty + 8 * i;
    tile[r][tx] = in[((b * CC + c0 + r) * NN) + n0 + tx];
  }
  __syncthreads();
  #pragma unroll
  for (int i = 0; i < 4; i++){
    int r = ty + 8 * i;
    float v = tile[tx][r];
    u16 hi = f2b(v);
    float lo = v - b2f(hi);
    size_t o = ((size_t)(b * NN + n0 + r) * CC) + c0 + tx;
    oh[o] = hi;
    ol[o] = f2b(lo);
  }
}

// ---- K1: exact f32 row squared norms (R18 lesson: no FP change ahead of a discrete
// selection; only bit-identical transforms admissible) -------------------------------
__global__ __launch_bounds__(256) void k_sq(const float* __restrict__ semb, const float* __restrict__ temb,
                                            float* __restrict__ xx, float* __restrict__ yy){
  int which = blockIdx.y;
  const float* in = which ? temb : semb;
  float* out = which ? yy : xx;
  int gid = blockIdx.x * 256 + threadIdx.x;   // 0..4095
  int b = gid >> 11, n = gid & 2047;
  float acc = 0.f;
  for (int c = 0; c < CC; c++){
    float v = in[((size_t)(b * CC + c)) * NN + n];
    acc += v * v;
  }
  out[gid] = acc;
}

// ---- K2: dist = xx - 2*A.B^T + yy, split-bf16 MFMA; gload_lds staging (R20) --------
__global__ __launch_bounds__(256) void k_gemm(const u16* __restrict__ Ah, const u16* __restrict__ Al,
                                              const u16* __restrict__ Bh, const u16* __restrict__ Bl,
                                              const float* __restrict__ xx, const float* __restrict__ yy,
                                              float* __restrict__ dist){
  __shared__ __align__(16) u16 lAh[128 * 64];
  __shared__ __align__(16) u16 lAl[128 * 64];
  __shared__ __align__(16) u16 lBh[128 * 64];
  __shared__ __align__(16) u16 lBl[128 * 64];
  int bz = blockIdx.z;
  const u16* Ahb = Ah + (size_t)bz * NN * CC;
  const u16* Alb = Al + (size_t)bz * NN * CC;
  const u16* Bhb = Bh + (size_t)bz * MM * CC;
  const u16* Blb = Bl + (size_t)bz * MM * CC;
  const float* xxb = xx + bz * NN;
  const float* yyb = yy + bz * MM;
  float* distb = dist + (size_t)bz * NN * MM;
  int n0 = blockIdx.y * 128, m0 = blockIdx.x * 128;
  int t = threadIdx.x;
  f32x4 acc[4][4];
  #pragma unroll
  for (int i = 0; i < 4; i++)
    #pragma unroll
    for (int j = 0; j < 4; j++){ f32x4 z = {0.f, 0.f, 0.f, 0.f}; acc[i][j] = z; }
  int w = t >> 6, lane = t & 63, lr = lane & 15, quad = lane >> 4;
  int wn = (w >> 1) * 64, wm = (w & 1) * 64;
  for (int kt = 0; kt < 8; kt++){
    int k0 = kt * 64;
    __syncthreads();
    #pragma unroll
    for (int s = 0; s < 4; s++){
      int ch = t + 256 * s;
      int rn = ch >> 3, k8 = (ch & 7) * 8;
      size_t oa = (size_t)(n0 + rn) * CC + k0 + k8;
      size_t ob = (size_t)(m0 + rn) * CC + k0 + k8;
      int ldsoff = ((t >> 6) * 64 + 256 * s) * 8;   // wave-uniform (u16 elems)
      gload_lds16(Ahb + oa, &lAh[ldsoff]);
      gload_lds16(Alb + oa, &lAl[ldsoff]);
      gload_lds16(Bhb + ob, &lBh[ldsoff]);
      gload_lds16(Blb + ob, &lBl[ldsoff]);
    }
    __syncthreads();
    #pragma unroll
    for (int kk = 0; kk < 2; kk++){
      int off = kk * 32 + quad * 8;
      bf16x8 afh[4], afl[4], bfh[4], bfl[4];
      #pragma unroll
      for (int i = 0; i < 4; i++){
        int ra = (wn + i * 16 + lr) * 64 + off;
        afh[i] = *(const bf16x8*)&lAh[ra];
        afl[i] = *(const bf16x8*)&lAl[ra];
      }
      #pragma unroll
      for (int j = 0; j < 4; j++){
        int rb = (wm + j * 16 + lr) * 64 + off;
        bfh[j] = *(const bf16x8*)&lBh[rb];
        bfl[j] = *(const bf16x8*)&lBl[rb];
      }
      #pragma unroll
      for (int i = 0; i < 4; i++)
        #pragma unroll
        for (int j = 0; j < 4; j++){
          acc[i][j] = __builtin_amdgcn_mfma_f32_16x16x32_bf16(afh[i], bfh[j], acc[i][j], 0, 0, 0);
          acc[i][j] = __builtin_amdgcn_mfma_f32_16x16x32_bf16(afh[i], bfl[j], acc[i][j], 0, 0, 0);
          acc[i][j] = __builtin_amdgcn_mfma_f32_16x16x32_bf16(afl[i], bfh[j], acc[i][j], 0, 0, 0);
        }
    }
  }
  #pragma unroll
  for (int i = 0; i < 4; i++){
    int nbase = n0 + wn + i * 16 + quad * 4;
    #pragma unroll
    for (int j = 0; j < 4; j++){
      int m = m0 + wm + j * 16 + lr;
      float yv = yyb[m];
      #pragma unroll
      for (int r = 0; r < 4; r++){
        distb[((size_t)(nbase + r)) * MM + m] = xxb[nbase + r] + yv - 2.0f * acc[i][j][r];
      }
    }
  }
}

// ---- K3: per-row min, softmax denom, scores row (R17/R21/R24) ----------------------
__global__ __launch_bounds__(256, 4) void k_rowstats(const float* __restrict__ dist,
                                                     float* __restrict__ mnA, float* __restrict__ Zr,
                                                     float* __restrict__ scores){
  __shared__ float red[256];
  __shared__ float wmin[4];
  int row = blockIdx.x, b = blockIdx.y, t = threadIdx.x;
  const float* dr = dist + ((size_t)b * NN + row) * MM;
  float* sr = scores + ((size_t)b * NN + row) * MM;
  float d[8];
  float mn = 3.4e38f;
  #pragma unroll
  for (int i = 0; i < 8; i++){ d[i] = sane(dr[t + 256 * i]); mn = fminf(mn, d[i]); }
  mn = blockMinExact(mn, wmin, t);
  float p[8];
  float z = 0.f;
  #pragma unroll
  for (int i = 0; i < 8; i++){ p[i] = expf(mn - d[i]); z += p[i]; }
  z = blockRed(z, red, t, 0);
  float zc = fmaxf(z, 1e-30f);
  if (t == 0){ mnA[b * NN + row] = mn; Zr[b * NN + row] = zc; }
  float iz = 1.0f / zc;
  #pragma unroll
  for (int i = 0; i < 8; i++) sr[t + 256 * i] = p[i] * iz;
}

// ---- K4: fused T/S/refined/rmm/src_corr/loss. R27: REVERTED to the R25 form (best
// measured: 42.8us). Post-mortems: R24 launch_bounds hint nulled (VGPR stayed 32);
// R25 register staging nulled (compiler re-folds); R26 async-DMA staging REGRESSED
// (60us: occupancy 66->19% lost more than 56KB-in-flight gained). Conclusion: this
// gather-bound kernel at 32 VGPR / 66% occupancy / 2.6 TB/s is at its structural
// operating point. No further attempts. --------------------------------------------
__global__ __launch_bounds__(256, 4) void k_fused(const float* __restrict__ dist, const float* __restrict__ scores,
                                                  const int* __restrict__ sidx1,
                                                  const int* __restrict__ idx2, const float* __restrict__ tgt,
                                                  float* __restrict__ s_corr, float* __restrict__ lossr){
  __shared__ float Trow[MM];
  __shared__ float wmin[4];
  int n = blockIdx.x, b = blockIdx.y, t = threadIdx.x;
  const float* distb = dist + (size_t)b * NN * MM;
  const float* scoresb = scores + (size_t)b * NN * MM;
  const int* sidx1b = sidx1 + (size_t)b * NN * KK1;
  const int* idx2b = idx2 + (size_t)b * MM * KK1;
  const float* tgtb = tgt + (size_t)b * 3 * MM;
  float* s_corrb = s_corr + (size_t)b * 3 * NN;
  float* lossb = lossr + b * NN;
  const float* dn_p = distb + (size_t)n * MM;
  float dn[8];
  #pragma unroll
  for (int i = 0; i < 8; i++) dn[i] = sane(dn_p[t + 256 * i]);
  const int4* i1v = (const int4*)(sidx1b + n * KK1);
  int4 i1a = i1v[0], i1b = i1v[1];
  int rj[7] = {i1a.y & 2047, i1a.z & 2047, i1a.w & 2047,
               i1b.x & 2047, i1b.y & 2047, i1b.z & 2047, i1b.w & 2047};
  float va[7][8];
  #pragma unroll
  for (int j = 0; j < 7; j++){
    const float* srp = scoresb + (size_t)rj[j] * MM;
    #pragma unroll
    for (int i = 0; i < 8; i++) va[j][i] = srp[t + 256 * i];
  }
  float tacc[8];
  #pragma unroll
  for (int i = 0; i < 8; i++){
    float s = 0.f;
    #pragma unroll
    for (int j = 0; j < 7; j++) s += va[j][i];
    tacc[i] = s;
  }
  #pragma unroll
  for (int i = 0; i < 8; i++) Trow[t + 256 * i] = tacc[i];
  __syncthreads();
  float rloc[8];
  float lmin = 3.4e38f;
  #pragma unroll
  for (int i = 0; i < 8; i++){
    int m = t + 256 * i;
    const int4* ipv = (const int4*)(idx2b + m * KK1);
    int4 ipa = ipv[0], ipb = ipv[1];
    float S = 0.f;
    S += Trow[ipa.y & 2047];
    S += Trow[ipa.z & 2047];
    S += Trow[ipa.w & 2047];
    S += Trow[ipb.x & 2047];
    S += Trow[ipb.y & 2047];
    S += Trow[ipb.z & 2047];
    S += Trow[ipb.w & 2047];
    float rv = sane(expf(1.0f - S / 7.0f) * dn[i]);
    rloc[i] = rv;
    lmin = fminf(lmin, rv);
  }
  // exact min; its barrier also guarantees all Trow reads finished before reuse
  float rmin = blockMinExact(lmin, wmin, t);
  float z = 0.f, s0 = 0.f, s1 = 0.f, s2 = 0.f;
  #pragma unroll
  for (int i = 0; i < 8; i++){
    int m = t + 256 * i;
    float p = expf(rmin - rloc[i]);
    z  += p;
    s0 += tgtb[0 * MM + m] * p;
    s1 += tgtb[1 * MM + m] * p;
    s2 += tgtb[2 * MM + m] * p;
  }
  f32x4 v4; v4.x = z; v4.y = s0; v4.z = s1; v4.w = s2;
  f32x4 r = blockRed4(v4, (f32x4*)Trow, t);   // Trow dead; identical tree order
  if (t == 0){
    float iZ = 1.0f / fmaxf(r.x, 1e-30f);
    s_corrb[0 * NN + n] = r.y * iZ;
    s_corrb[1 * NN + n] = r.z * iZ;
    s_corrb[2 * NN + n] = r.w * iZ;
    lossb[n] = -logf(fminf(iZ, 1.0f) + 1e-15f);  // pred at onehot == rowmax(rmm) == 1/Z
  }
}

// ---- K5: discriminator MLP — R14: scalar-W2 + e-range wave split -------------------
__global__ __launch_bounds__(256, 4) void k_disc(const float* __restrict__ s_corr, const float* __restrict__ src,
                                                 const float* __restrict__ sknn, const int* __restrict__ sidx,
                                                 const float* __restrict__ W1, const float* __restrict__ b1,
                                                 const float* __restrict__ W2, const float* __restrict__ b2,
                                                 const float* __restrict__ W3, const float* __restrict__ b3,
                                                 float* __restrict__ sArr){
  __shared__ float term[64][129];
  int t = threadIdx.x;
  int b = blockIdx.y;
  int p = t & 63;
  int n = blockIdx.x * 4 + (p >> 4);
  int kk = p & 15;
  int eh = t >> 6;
  int nk = sidx[((b * NN + n) * KK) + kk] & 2047;
  float f[6];
  #pragma unroll
  for (int c = 0; c < 3; c++){
    f[c]     = s_corr[(b * 3 + c) * NN + n] - s_corr[(b * 3 + c) * NN + nk];
    f[3 + c] = src[(b * 3 + c) * NN + n] - sknn[((size_t)(b * NN + n) * KK + kk) * 3 + c];
  }
  #define L1D(d) ({ float a_ = b1[(d)];              \
                    a_ += f[0] * W1[(d) * 6 + 0];    \
                    a_ += f[1] * W1[(d) * 6 + 1];    \
                    a_ += f[2] * W1[(d) * 6 + 2];    \
                    a_ += f[3] * W1[(d) * 6 + 3];    \
                    a_ += f[4] * W1[(d) * 6 + 4];    \
                    a_ += f[5] * W1[(d) * 6 + 5];    \
                    fmaxf(a_, 0.f); })
  #define HSET(i) f32x4 h##i;                  \
                  h##i.x = L1D(4 * (i) + 0);   \
                  h##i.y = L1D(4 * (i) + 1);   \
                  h##i.z = L1D(4 * (i) + 2);   \
                  h##i.w = L1D(4 * (i) + 3);
  HSET(0) HSET(1) HSET(2) HSET(3) HSET(4) HSET(5) HSET(6) HSET(7)
  HSET(8) HSET(9) HSET(10) HSET(11) HSET(12) HSET(13) HSET(14) HSET(15)
  #undef HSET
  #undef L1D
  int e0 = __builtin_amdgcn_readfirstlane(eh * 32);
  for (int j = 0; j < 32; j++){
    int e = e0 + j;
    float a = b2[e];
    const f32x4* w4 = (const f32x4*)&W2[e * 64];
    #define QSTEP(i) { f32x4 wv = w4[i]; a += wv.x * h##i.x + wv.y * h##i.y + wv.z * h##i.z + wv.w * h##i.w; }
    QSTEP(0) QSTEP(1) QSTEP(2) QSTEP(3) QSTEP(4) QSTEP(5) QSTEP(6) QSTEP(7)
    QSTEP(8) QSTEP(9) QSTEP(10) QSTEP(11) QSTEP(12) QSTEP(13) QSTEP(14) QSTEP(15)
    #undef QSTEP
    term[p][e] = fmaxf(a, 0.f);
  }
  __syncthreads();
  if (t < 64){
    float sacc = b3[0];
    #pragma unroll 4
    for (int e = 0; e < 128; e++) sacc += W3[e] * term[t][e];
    if (!(fabsf(sacc) < 1e30f)) sacc = -1e30f;
    #pragma unroll
    for (int off = 1; off < 16; off <<= 1) sacc = fmaxf(sacc, __shfl_xor(sacc, off, 16));
    if (kk == 0) sArr[b * NN + n] = sacc;
  }
}

// ---- K6+K7+K8 merged (R21/R22/R23 structure; f32 SVD, named scalars) ---------------
__global__ __launch_bounds__(256) void k_rankrig(const float* __restrict__ sArr, const float* __restrict__ src,
                                                 const float* __restrict__ s_corr, int* __restrict__ topi,
                                                 float* __restrict__ Rt, float* __restrict__ out){
  __shared__ float wrow[NN];
  __shared__ float red[256];
  __shared__ f32x4 red4[256];
  __shared__ int pc[4][64];
  int b = blockIdx.y, t = threadIdx.x;
  // ---- softmax (verbatim k_softw) -> wrow (feeds rank -> topi: DISCRETE, verbatim) --
  const float* sp = sArr + b * NN;
  float sv[8];
  float mx = -3.4e38f;
  #pragma unroll
  for (int i = 0; i < 8; i++){
    float v = sp[t + 256 * i];
    if (!(fabsf(v) < 1e30f)) v = -1e30f;
    sv[i] = v; mx = fmaxf(mx, v);
  }
  mx = blockRed(mx, red, t, 2);
  float z = 0.f;
  #pragma unroll
  for (int i = 0; i < 8; i++) z += expf(sv[i] - mx);
  z = blockRed(z, red, t, 0);
  float iz = 1.0f / fmaxf(z, 1e-30f);
  #pragma unroll
  for (int i = 0; i < 8; i++) wrow[t + 256 * i] = expf(sv[i] - mx) * iz;
  __syncthreads();
  // ---- rank (verbatim R15 body) ----
  int tn = t & 63, tj = t >> 6;
  int n = blockIdx.x * 64 + tn;
  float wn = wrow[n];
  int j0 = tj * 512;
  const f32x4* w4 = (const f32x4*)&wrow[j0];
  int cnt = 0;
  #pragma unroll 4
  for (int q = 0; q < 128; q++){
    f32x4 wv = w4[q];
    int j = j0 + q * 4;
    cnt += (wv.x > wn) || ((wv.x == wn) && (j + 0 < n));
    cnt += (wv.y > wn) || ((wv.y == wn) && (j + 1 < n));
    cnt += (wv.z > wn) || ((wv.z == wn) && (j + 2 < n));
    cnt += (wv.w > wn) || ((wv.w == wn) && (j + 3 < n));
  }
  pc[tj][tn] = cnt;
  __syncthreads();
  if (t < 64){
    int c = pc[0][t] + pc[1][t] + pc[2][t] + pc[3][t];
    if (c < KEY) topi[b * KEY + c] = blockIdx.x * 64 + t;
  }
  if (blockIdx.x != 0) return;
  // ---- rigid: centroids + H via blockRed4 (bit-identical sums) ----
  float wsum = 0, a0 = 0, a1 = 0, a2 = 0, c0 = 0, c1 = 0, c2 = 0;
  for (int n2 = t; n2 < NN; n2 += 256){
    float wv = wrow[n2];
    float s0 = src[(b * 3 + 0) * NN + n2];
    float s1 = src[(b * 3 + 1) * NN + n2];
    float s2 = src[(b * 3 + 2) * NN + n2];
    float q0 = s_corr[(b * 3 + 0) * NN + n2];
    float q1 = s_corr[(b * 3 + 1) * NN + n2];
    float q2 = s_corr[(b * 3 + 2) * NN + n2];
    wsum += wv; a0 += wv * s0; a1 += wv * s1; a2 += wv * s2;
    c0 += wv * q0; c1 += wv * q1; c2 += wv * q2;
  }
  f32x4 pk1; pk1.x = wsum; pk1.y = a0; pk1.z = a1; pk1.w = a2;
  pk1 = blockRed4(pk1, red4, t);
  f32x4 pk2; pk2.x = c0; pk2.y = c1; pk2.z = c2; pk2.w = 0.f;
  pk2 = blockRed4(pk2, red4, t);
  wsum = pk1.x; a0 = pk1.y; a1 = pk1.z; a2 = pk1.w;
  c0 = pk2.x; c1 = pk2.y; c2 = pk2.z;
  float inv = 1.0f / fmaxf(wsum, 1e-30f);
  float cs0 = a0 * inv, cs1 = a1 * inv, cs2 = a2 * inv;
  float ct0 = c0 * inv, ct1 = c1 * inv, ct2 = c2 * inv;
  float h[9] = {0, 0, 0, 0, 0, 0, 0, 0, 0};
  for (int n2 = t; n2 < NN; n2 += 256){
    float wv = wrow[n2];
    float ds0 = src[(b * 3 + 0) * NN + n2] - cs0;
    float ds1 = src[(b * 3 + 1) * NN + n2] - cs1;
    float ds2 = src[(b * 3 + 2) * NN + n2] - cs2;
    float dc0 = s_corr[(b * 3 + 0) * NN + n2] - ct0;
    float dc1 = s_corr[(b * 3 + 1) * NN + n2] - ct1;
    float dc2 = s_corr[(b * 3 + 2) * NN + n2] - ct2;
    h[0] += wv * ds0 * dc0; h[1] += wv * ds0 * dc1; h[2] += wv * ds0 * dc2;
    h[3] += wv * ds1 * dc0; h[4] += wv * ds1 * dc1; h[5] += wv * ds1 * dc2;
    h[6] += wv * ds2 * dc0; h[7] += wv * ds2 * dc1; h[8] += wv * ds2 * dc2;
  }
  f32x4 ph1; ph1.x = h[0]; ph1.y = h[1]; ph1.z = h[2]; ph1.w = h[3];
  ph1 = blockRed4(ph1, red4, t);
  f32x4 ph2; ph2.x = h[4]; ph2.y = h[5]; ph2.z = h[6]; ph2.w = h[7];
  ph2 = blockRed4(ph2, red4, t);
  float h8 = blockRed(h[8], red, t, 0);
  if (t == 0){
    // ---- all-register 3x3 SVD, f32 (static pivot enumeration) ----
    float Hm00 = ph1.x, Hm01 = ph1.y, Hm02 = ph1.z;
    float Hm10 = ph1.w, Hm11 = ph2.x, Hm12 = ph2.y;
    float Hm20 = ph2.z, Hm21 = ph2.w, Hm22 = h8;
    float k00 = Hm00 * Hm00 + Hm10 * Hm10 + Hm20 * Hm20;
    float k01 = Hm00 * Hm01 + Hm10 * Hm11 + Hm20 * Hm21;
    float k02 = Hm00 * Hm02 + Hm10 * Hm12 + Hm20 * Hm22;
    float k10 = k01, k11 = Hm01 * Hm01 + Hm11 * Hm11 + Hm21 * Hm21;
    float k12 = Hm01 * Hm02 + Hm11 * Hm12 + Hm21 * Hm22;
    float k20 = k02, k21 = k12;
    float k22 = Hm02 * Hm02 + Hm12 * Hm12 + Hm22 * Hm22;
    float v00 = 1, v01 = 0, v02 = 0, v10 = 0, v11 = 1, v12 = 0, v20 = 0, v21 = 0, v22 = 1;
    float ksc = fabsf(k00) + fabsf(k11) + fabsf(k22) + 1e-30f;
    #define ROT2(A, B) { float ra = A, rb = B; A = cc2 * ra - sn * rb; B = sn * ra + cc2 * rb; }
    for (int sweep = 0; sweep < 30; sweep++){
      float m01 = fabsf(k01), m02 = fabsf(k02), m12 = fabsf(k12);
      int cse = 0; float mx2 = m01;
      if (m02 > mx2){ mx2 = m02; cse = 1; }
      if (m12 > mx2){ mx2 = m12; cse = 2; }
      if (mx2 <= 1e-6f * ksc) break;
      float app, aqq, apq;
      if (cse == 0){ app = k00; aqq = k11; apq = k01; }
      else if (cse == 1){ app = k00; aqq = k22; apq = k02; }
      else { app = k11; aqq = k22; apq = k12; }
      float tau = (aqq - app) / (2.0f * apq);
      float tt = ((tau >= 0) ? 1.0f : -1.0f) / (fabsf(tau) + sqrtf(1.0f + tau * tau));
      float cc2 = 1.0f / sqrtf(1.0f + tt * tt), sn = tt * cc2;
      if (cse == 0){        // (p,q)=(0,1)
        ROT2(k00, k01) ROT2(k10, k11) ROT2(k20, k21)
        ROT2(k00, k10) ROT2(k01, k11) ROT2(k02, k12)
        ROT2(v00, v01) ROT2(v10, v11) ROT2(v20, v21)
      } else if (cse == 1){ // (p,q)=(0,2)
        ROT2(k00, k02) ROT2(k10, k12) ROT2(k20, k22)
        ROT2(k00, k20) ROT2(k01, k21) ROT2(k02, k22)
        ROT2(v00, v02) ROT2(v10, v12) ROT2(v20, v22)
      } else {              // (p,q)=(1,2)
        ROT2(k01, k02) ROT2(k11, k12) ROT2(k21, k22)
        ROT2(k10, k20) ROT2(k11, k21) ROT2(k12, k22)
        ROT2(v01, v02) ROT2(v11, v12) ROT2(v21, v22)
      }
    }
    #undef ROT2
    float l0 = k00, l1 = k11, l2 = k22; int id0 = 0, id1 = 1, id2 = 2;
    float lt; int it;
    if (l0 < l1){ lt = l0; l0 = l1; l1 = lt; it = id0; id0 = id1; id1 = it; }
    if (l0 < l2){ lt = l0; l0 = l2; l2 = lt; it = id0; id0 = id2; id2 = it; }
    if (l1 < l2){ lt = l1; l1 = l2; l2 = lt; it = id1; id1 = id2; id2 = it; }
    float Vs00, Vs10, Vs20, Vs01, Vs11, Vs21, Vs02, Vs12, Vs22;
    float u00 = 0, u10 = 0, u20 = 0, u01 = 0, u11 = 0, u21 = 0, u02 = 0, u12 = 0, u22 = 0;
    #define GETCOL(j, cA, cB, cC) { if ((j) == 0){ cA = v00; cB = v10; cC = v20; } \
                                    else if ((j) == 1){ cA = v01; cB = v11; cC = v21; } \
                                    else { cA = v02; cB = v12; cC = v22; } }
    {
      float cA, cB, cC; GETCOL(id0, cA, cB, cC);
      Vs00 = cA; Vs10 = cB; Vs20 = cC;
      float uu0 = Hm00 * cA + Hm01 * cB + Hm02 * cC;
      float uu1 = Hm10 * cA + Hm11 * cB + Hm12 * cC;
      float uu2 = Hm20 * cA + Hm21 * cB + Hm22 * cC;
      float nrm = sqrtf(uu0 * uu0 + uu1 * uu1 + uu2 * uu2);
      if (nrm > 1e-20f){ u00 = uu0 / nrm; u10 = uu1 / nrm; u20 = uu2 / nrm; }
      else { u00 = 1; u10 = 0; u20 = 0; }
    }
    {
      float cA, cB, cC; GETCOL(id1, cA, cB, cC);
      Vs01 = cA; Vs11 = cB; Vs21 = cC;
      float uu0 = Hm00 * cA + Hm01 * cB + Hm02 * cC;
      float uu1 = Hm10 * cA + Hm11 * cB + Hm12 * cC;
      float uu2 = Hm20 * cA + Hm21 * cB + Hm22 * cC;
      float nrm = sqrtf(uu0 * uu0 + uu1 * uu1 + uu2 * uu2);
      if (nrm > 1e-20f){ u01 = uu0 / nrm; u11 = uu1 / nrm; u21 = uu2 / nrm; }
      else {
        float x0 = u10 * u21 - u20 * u11;
        float x1 = u20 * u01 - u00 * u21;
        float x2 = u00 * u11 - u10 * u01;
        float nn2 = sqrtf(x0 * x0 + x1 * x1 + x2 * x2);
        if (nn2 < 1e-20f){ x0 = 1; x1 = 0; x2 = 0; nn2 = 1; }
        u01 = x0 / nn2; u11 = x1 / nn2; u21 = x2 / nn2;
      }
    }
    {
      float cA, cB, cC; GETCOL(id2, cA, cB, cC);
      Vs02 = cA; Vs12 = cB; Vs22 = cC;
      float uu0 = Hm00 * cA + Hm01 * cB + Hm02 * cC;
      float uu1 = Hm10 * cA + Hm11 * cB + Hm12 * cC;
      float uu2 = Hm20 * cA + Hm21 * cB + Hm22 * cC;
      float nrm = sqrtf(uu0 * uu0 + uu1 * uu1 + uu2 * uu2);
      if (nrm > 1e-20f){ u02 = uu0 / nrm; u12 = uu1 / nrm; u22 = uu2 / nrm; }
      else {
        float x0 = u10 * u21 - u20 * u11;
        float x1 = u20 * u01 - u00 * u21;
        float x2 = u00 * u11 - u10 * u01;
        float nn2 = sqrtf(x0 * x0 + x1 * x1 + x2 * x2);
        if (nn2 < 1e-20f){ x0 = 1; x1 = 0; x2 = 0; nn2 = 1; }
        u02 = x0 / nn2; u12 = x1 / nn2; u22 = x2 / nn2;
      }
    }
    #undef GETCOL
    float ddU = u00 * (u11 * u22 - u12 * u21) - u01 * (u10 * u22 - u12 * u20) + u02 * (u10 * u21 - u11 * u20);
    float ddV = Vs00 * (Vs11 * Vs22 - Vs12 * Vs21) - Vs01 * (Vs10 * Vs22 - Vs12 * Vs20) + Vs02 * (Vs10 * Vs21 - Vs11 * Vs20);
    float dd = ddU * ddV;
    float Rm00 = Vs00 * u00 + Vs01 * u01 + dd * Vs02 * u02;
    float Rm01 = Vs00 * u10 + Vs01 * u11 + dd * Vs02 * u12;
    float Rm02 = Vs00 * u20 + Vs01 * u21 + dd * Vs02 * u22;
    float Rm10 = Vs10 * u00 + Vs11 * u01 + dd * Vs12 * u02;
    float Rm11 = Vs10 * u10 + Vs11 * u11 + dd * Vs12 * u12;
    float Rm12 = Vs10 * u20 + Vs11 * u21 + dd * Vs12 * u22;
    float Rm20 = Vs20 * u00 + Vs21 * u01 + dd * Vs22 * u02;
    float Rm21 = Vs20 * u10 + Vs21 * u11 + dd * Vs22 * u12;
    float Rm22 = Vs20 * u20 + Vs21 * u21 + dd * Vs22 * u22;
    float tv0 = ct0 - (Rm00 * cs0 + Rm01 * cs1 + Rm02 * cs2);
    float tv1 = ct1 - (Rm10 * cs0 + Rm11 * cs1 + Rm12 * cs2);
    float tv2 = ct2 - (Rm20 * cs0 + Rm21 * cs1 + Rm22 * cs2);
    Rt[b * 12 + 0] = Rm00; out[b * 9 + 0] = Rm00;
    Rt[b * 12 + 1] = Rm01; out[b * 9 + 1] = Rm01;
    Rt[b * 12 + 2] = Rm02; out[b * 9 + 2] = Rm02;
    Rt[b * 12 + 3] = Rm10; out[b * 9 + 3] = Rm10;
    Rt[b * 12 + 4] = Rm11; out[b * 9 + 4] = Rm11;
    Rt[b * 12 + 5] = Rm12; out[b * 9 + 5] = Rm12;
    Rt[b * 12 + 6] = Rm20; out[b * 9 + 6] = Rm20;
    Rt[b * 12 + 7] = Rm21; out[b * 9 + 7] = Rm21;
    Rt[b * 12 + 8] = Rm22; out[b * 9 + 8] = Rm22;
    Rt[b * 12 + 9]  = tv0; out[18 + b * 3 + 0] = tv0;
    Rt[b * 12 + 10] = tv1; out[18 + b * 3 + 1] = tv1;
    Rt[b * 12 + 11] = tv2; out[18 + b * 3 + 2] = tv2;
  }
}

// ---- K10 (+K11 merged): keypoint gathers; block x==64,b==0 computes loss_scl -------
__global__ __launch_bounds__(256) void k_out(const int* __restrict__ topi, const int* __restrict__ sidx,
                                             const float* __restrict__ src, const float* __restrict__ s_corr,
                                             const float* __restrict__ Rt, const float* __restrict__ loss_row,
                                             float* __restrict__ out){
  __shared__ float red[256];
  int b = blockIdx.y, t = threadIdx.x;
  if (blockIdx.x == 64){
    if (b != 0) return;
    float acc = 0.f;
    for (int i = t; i < BB * KEY; i += 256){
      int bb = i >> 10, r = i & 1023;
      int n = topi[bb * KEY + r] & 2047;
      acc += loss_row[bb * NN + n];
    }
    acc = blockRed(acc, red, t, 0);
    if (t == 0) out[208920] = acc / 2048.0f;
    return;
  }
  int rr = t >> 4, kk = t & 15;
  int r = blockIdx.x * 16 + rr;
  int ns = topi[b * KEY + r] & 2047;
  int nk = sidx[(b * NN + ns) * KK + kk] & 2047;
  const float* R = Rt + b * 12;
  float sns0 = src[(b * 3 + 0) * NN + ns];
  float sns1 = src[(b * 3 + 1) * NN + ns];
  float sns2 = src[(b * 3 + 2) * NN + ns];
  float snk0 = src[(b * 3 + 0) * NN + nk];
  float snk1 = src[(b * 3 + 1) * NN + nk];
  float snk2 = src[(b * 3 + 2) * NN + nk];
  float* o_sk  = out + 24;
  float* o_tk  = out + 6168;
  float* o_skk = out + 12312;
  float* o_tkk = out + 110616;
  #pragma unroll
  for (int c = 0; c < 3; c++){
    float cv  = s_corr[(b * 3 + c) * NN + ns];
    float ck  = s_corr[(b * 3 + c) * NN + nk];
    o_tkk[(((b * 3 + c) * KEY + r) * KK) + kk] = cv - ck;
    float sv  = R[c * 3 + 0] * sns0 + R[c * 3 + 1] * sns1 + R[c * 3 + 2] * sns2 + R[9 + c];
    float sk2 = R[c * 3 + 0] * snk0 + R[c * 3 + 1] * snk1 + R[c * 3 + 2] * snk2 + R[9 + c];
    o_skk[(((b * 3 + c) * KEY + r) * KK) + kk] = sv - sk2;
    if (kk == 0){
      o_sk[(b * 3 + c) * KEY + r] = sns0 * (c == 0) + sns1 * (c == 1) + sns2 * (c == 2);
      o_tk[(b * 3 + c) * KEY + r] = cv;
    }
  }
}

extern "C" void kernel_launch(void* const* d_in, const int* in_sizes, int n_in,
                              void* d_out, int out_size, void* d_ws, size_t ws_size,
                              hipStream_t stream){
  const float* src  = (const float*)d_in[0];
  const float* tgt  = (const float*)d_in[1];
  const float* semb = (const float*)d_in[2];
  const float* temb = (const float*)d_in[3];
  const float* sknn = (const float*)d_in[4];
  const float* W1 = (const float*)d_in[6];
  const float* b1 = (const float*)d_in[7];
  const float* W2 = (const float*)d_in[8];
  const float* b2 = (const float*)d_in[9];
  const float* W3 = (const float*)d_in[10];
  const float* b3 = (const float*)d_in[11];
  const int* sidx  = (const int*)d_in[12];
  const int* sidx1 = (const int*)d_in[13];
  const int* idx2  = (const int*)d_in[14];
  float* out = (float*)d_out;

  // workspace layout (peak ~84 MB; harness allocates 256 MiB per fill evidence)
  char* w = (char*)d_ws;
  u16* Ah = (u16*)(w);                               // 4 MB each (B,N,C) bf16 split
  u16* Al = Ah + (size_t)BB * NN * CC;
  u16* Bh = Al + (size_t)BB * NN * CC;
  u16* Bl = Bh + (size_t)BB * MM * CC;
  float* dist = (float*)(Bl + (size_t)BB * MM * CC); // 33.55 MB (B,N,M) f32
  float* scores = dist + (size_t)BB * NN * MM;       // 33.55 MB (B,N,M) f32
  char* tail = (char*)(scores + (size_t)BB * NN * MM);
  float* xx = (float*)tail;                          // B*N
  float* yy = xx + BB * NN;                          // B*M
  float* mnA = yy + BB * MM;                         // B*N
  float* Zr = mnA + BB * NN;                         // B*N
  float* s_corr = Zr + BB * NN;                      // B*3*N
  float* loss_row = s_corr + BB * 3 * NN;            // B*N
  float* sArr = loss_row + BB * NN;                  // B*N
  int* topi = (int*)(sArr + BB * NN);                // B*KEY
  float* Rt = (float*)(topi + BB * KEY);             // B*12

  k_trans<<<dim3(16, 64, 4), dim3(32, 8), 0, stream>>>(semb, temb, Ah, Al, Bh, Bl);
  k_sq<<<dim3(16, 2), 256, 0, stream>>>(semb, temb, xx, yy);
  k_gemm<<<dim3(16, 16, BB), 256, 0, stream>>>(Ah, Al, Bh, Bl, xx, yy, dist);
  k_rowstats<<<dim3(NN, BB), 256, 0, stream>>>(dist, mnA, Zr, scores);
  k_fused<<<dim3(NN, BB), 256, 0, stream>>>(dist, scores, sidx1, idx2, tgt, s_corr, loss_row);
  k_disc<<<dim3(NN / 4, BB), 256, 0, stream>>>(s_corr, src, sknn, sidx, W1, b1, W2, b2, W3, b3, sArr);
  k_rankrig<<<dim3(32, BB), 256, 0, stream>>>(sArr, src, s_corr, topi, Rt, out);
  k_out<<<dim3(65, BB), 256, 0, stream>>>(topi, sidx, src, s_corr, Rt, loss_row, out);
}